// Round 1
// baseline (580.992 us; speedup 1.0000x reference)
//
#include <hip/hip_runtime.h>
#include <math.h>

#define CC   256
#define BB   16
#define HH   128
#define WW   128
#define NP   14              // 2 + 4 + 8 proto slots
#define HW   (HH*WW)         // 16384
#define MAT  (CC*CC)         // 65536
#define PRS  (NP*CC)         // 3584 floats per (b,h)
#define NBH  (BB*HH)         // 2048

// ---------------------------------------------------------------------------
// k_mats1: MT[i][d][c] = M_i[c][d] = sum_o Wf[i,o,c] * Wp[i,o,d]
//          ET[i][c2][o] = E_i[o][c2] = sum_c3 Wfuse[o, i*C+c3] * Wo[i,c3,c2]
// ---------------------------------------------------------------------------
__global__ __launch_bounds__(256) void k_mats1(
    const float* __restrict__ Wp, const float* __restrict__ Wf,
    const float* __restrict__ Wo, const float* __restrict__ Wfu,
    float* __restrict__ MT, float* __restrict__ ET)
{
    int idx = blockIdx.x;
    int t = threadIdx.x;
    if (idx < 3*CC) {
        int i = idx >> 8, d = idx & 255;
        const float* wf = Wf + (size_t)i*MAT;
        const float* wp = Wp + (size_t)i*MAT;
        float acc = 0.f;
        for (int o = 0; o < CC; ++o)
            acc += wf[o*CC + t] * wp[o*CC + d];      // wf coalesced, wp uniform
        MT[(size_t)i*MAT + d*CC + t] = acc;
    } else {
        idx -= 3*CC;
        int i = idx >> 8, c2 = idx & 255;
        const float* wo = Wo + (size_t)i*MAT;
        float acc = 0.f;
        for (int c3 = 0; c3 < CC; ++c3)
            acc += Wfu[t*(3*CC) + i*CC + c3] * wo[c3*CC + c2];  // wo uniform
        ET[(size_t)i*MAT + c2*CC + t] = acc;
    }
}

// ---------------------------------------------------------------------------
// k_mats2: VT[i][d][o] = V_i[o][d] = sum_c E_i[o][c] * Wp[i,c,d]
// ---------------------------------------------------------------------------
__global__ __launch_bounds__(256) void k_mats2(
    const float* __restrict__ Wp, const float* __restrict__ ET,
    float* __restrict__ VT)
{
    int idx = blockIdx.x;
    int i = idx >> 8, d = idx & 255;
    int o = threadIdx.x;
    const float* et = ET + (size_t)i*MAT;
    const float* wp = Wp + (size_t)i*MAT;
    float acc = 0.f;
    for (int c = 0; c < CC; ++c)
        acc += et[c*CC + o] * wp[c*CC + d];          // et coalesced, wp uniform
    VT[(size_t)i*MAT + d*CC + o] = acc;
}

// ---------------------------------------------------------------------------
// k_pool: pr[bh][c][p] : p in [0,2)=P2 means, [2,6)=P4, [6,14)=P8
// block = 256 threads over one (b,h) row. 16-lane shuffle reduce -> 8 fine bins.
// ---------------------------------------------------------------------------
__global__ __launch_bounds__(256) void k_pool(
    const float* __restrict__ x, float* __restrict__ pr)
{
    int bh = blockIdx.x;
    int b = bh >> 7, h = bh & 127;
    int t = threadIdx.x;
    int w = t & 127, chalf = t >> 7;
    __shared__ float bins[CC][9];                    // pad 9: conflict-free reads
    size_t base = (size_t)b*CC*HW + (size_t)h*WW + w;
    for (int i = 0; i < 128; ++i) {
        int c = chalf*128 + i;
        float v = x[base + (size_t)c*HW];
        v += __shfl_xor(v, 1);
        v += __shfl_xor(v, 2);
        v += __shfl_xor(v, 4);
        v += __shfl_xor(v, 8);                       // sum within 16-lane groups
        if ((w & 15) == 0) bins[c][w >> 4] = v;
    }
    __syncthreads();
    int c = t;
    float b8[8];
    #pragma unroll
    for (int j = 0; j < 8; ++j) b8[j] = bins[c][j];
    float* prb = pr + (size_t)bh*PRS + c*NP;
    prb[0] = (b8[0]+b8[1]+b8[2]+b8[3]) * (1.f/64.f);
    prb[1] = (b8[4]+b8[5]+b8[6]+b8[7]) * (1.f/64.f);
    #pragma unroll
    for (int j = 0; j < 4; ++j) prb[2+j] = (b8[2*j]+b8[2*j+1]) * (1.f/32.f);
    #pragma unroll
    for (int j = 0; j < 8; ++j) prb[6+j] = b8[j] * (1.f/16.f);
}

// ---------------------------------------------------------------------------
// k_proj: mproj[bh][c][p] = sum_d M[c,d] pr[bh][d][p]   (MT[d][c] coalesced)
//         vproj[bh][o][p] = sum_d V[o,d] pr[bh][d][p]
// 4 bh per block to amortize matrix L2 traffic; per-branch passes cap VGPRs.
// ---------------------------------------------------------------------------
template<int PI, int OFF>
__device__ __forceinline__ void proj_pass(
    int i, int bh0, int t,
    const float* __restrict__ MT, const float* __restrict__ VT,
    const float* __restrict__ pr,
    float* __restrict__ mproj, float* __restrict__ vproj)
{
    float am[4][PI] = {};
    float av[4][PI] = {};
    const float* mt = MT + (size_t)i*MAT;
    const float* vt = VT + (size_t)i*MAT;
    for (int d = 0; d < CC; ++d) {
        float m = mt[d*CC + t];
        float v = vt[d*CC + t];
        #pragma unroll
        for (int g = 0; g < 4; ++g) {
            const float* prb = pr + (size_t)(bh0+g)*PRS + d*NP + OFF; // uniform
            #pragma unroll
            for (int pl = 0; pl < PI; ++pl) {
                float s = prb[pl];
                am[g][pl] += m * s;
                av[g][pl] += v * s;
            }
        }
    }
    #pragma unroll
    for (int g = 0; g < 4; ++g) {
        float* mo = mproj + (size_t)(bh0+g)*PRS + t*NP + OFF;
        float* vo = vproj + (size_t)(bh0+g)*PRS + t*NP + OFF;
        #pragma unroll
        for (int pl = 0; pl < PI; ++pl) { mo[pl] = am[g][pl]; vo[pl] = av[g][pl]; }
    }
}

__global__ __launch_bounds__(256) void k_proj(
    const float* __restrict__ MT, const float* __restrict__ VT,
    const float* __restrict__ pr,
    float* __restrict__ mproj, float* __restrict__ vproj)
{
    int bh0 = blockIdx.x * 4;
    int t = threadIdx.x;
    proj_pass<2,0>(0, bh0, t, MT, VT, pr, mproj, vproj);
    proj_pass<4,2>(1, bh0, t, MT, VT, pr, mproj, vproj);
    proj_pass<8,6>(2, bh0, t, MT, VT, pr, mproj, vproj);
}

// ---------------------------------------------------------------------------
// k_main: per (b,h) row. att[w][p] = (1/16) sum_c x[c][w] mproj[c][p];
// softmax per branch; out[o][w] = x[o][w] + sum_p att[p] vproj[o][p].
// mproj/vproj indices are wave-uniform -> scalar loads; att stays in VGPRs.
// ---------------------------------------------------------------------------
template<int L>
__device__ __forceinline__ void softmax_l(float* a) {
    float m = a[0];
    #pragma unroll
    for (int j = 1; j < L; ++j) m = fmaxf(m, a[j]);
    float s = 0.f;
    #pragma unroll
    for (int j = 0; j < L; ++j) { a[j] = __expf(a[j] - m); s += a[j]; }
    float r = 1.f / s;
    #pragma unroll
    for (int j = 0; j < L; ++j) a[j] *= r;
}

__global__ __launch_bounds__(128) void k_main(
    const float* __restrict__ x, const float* __restrict__ mproj,
    const float* __restrict__ vproj, float* __restrict__ out)
{
    int bh = blockIdx.x;
    int b = bh >> 7, h = bh & 127;
    int w = threadIdx.x;
    const float* mp = mproj + (size_t)bh*PRS;
    const float* vp = vproj + (size_t)bh*PRS;
    size_t base = (size_t)b*CC*HW + (size_t)h*WW + w;

    float att[NP];
    #pragma unroll
    for (int p = 0; p < NP; ++p) att[p] = 0.f;

    for (int c = 0; c < CC; ++c) {
        float xv = x[base + (size_t)c*HW];
        const float* mpc = mp + c*NP;                // uniform address
        #pragma unroll
        for (int p = 0; p < NP; ++p) att[p] += xv * mpc[p];
    }
    #pragma unroll
    for (int p = 0; p < NP; ++p) att[p] *= 0.0625f;  // 1/sqrt(256)

    softmax_l<2>(att + 0);
    softmax_l<4>(att + 2);
    softmax_l<8>(att + 6);

    for (int o = 0; o < CC; ++o) {
        float acc = x[base + (size_t)o*HW];
        const float* vpo = vp + o*NP;                // uniform address
        #pragma unroll
        for (int p = 0; p < NP; ++p) acc += att[p] * vpo[p];
        out[base + (size_t)o*HW] = acc;
    }
}

// ---------------------------------------------------------------------------
extern "C" void kernel_launch(void* const* d_in, const int* in_sizes, int n_in,
                              void* d_out, int out_size, void* d_ws, size_t ws_size,
                              hipStream_t stream)
{
    (void)in_sizes; (void)n_in; (void)out_size; (void)ws_size;
    const float* x   = (const float*)d_in[0];
    const float* Wp  = (const float*)d_in[1];
    const float* Wf  = (const float*)d_in[2];
    const float* Wo  = (const float*)d_in[3];
    const float* Wfu = (const float*)d_in[4];
    float* out = (float*)d_out;

    float* ws    = (float*)d_ws;
    float* MT    = ws;                         // 3*MAT
    float* ET    = MT + (size_t)3*MAT;         // 3*MAT
    float* VT    = ET + (size_t)3*MAT;         // 3*MAT
    float* pr    = VT + (size_t)3*MAT;         // NBH*PRS
    float* mproj = pr + (size_t)NBH*PRS;       // NBH*PRS
    float* vproj = mproj + (size_t)NBH*PRS;    // NBH*PRS
    // total ws use: (9*65536 + 3*2048*3584)*4 B ~= 90.4 MB

    k_mats1<<<dim3(6*CC), dim3(256), 0, stream>>>(Wp, Wf, Wo, Wfu, MT, ET);
    k_mats2<<<dim3(3*CC), dim3(256), 0, stream>>>(Wp, ET, VT);
    k_pool <<<dim3(NBH),  dim3(256), 0, stream>>>(x, pr);
    k_proj <<<dim3(NBH/4),dim3(256), 0, stream>>>(MT, VT, pr, mproj, vproj);
    k_main <<<dim3(NBH),  dim3(128), 0, stream>>>(x, mproj, vproj, out);
}

// Round 2
// 430.954 us; speedup vs baseline: 1.3482x; 1.3482x over previous
//
#include <hip/hip_runtime.h>
#include <hip/hip_bf16.h>
#include <math.h>

#define CC   256
#define BB   16
#define HH   128
#define WW   128
#define HW   (HH*WW)         // 16384
#define MAT  (CC*CC)         // 65536
#define NBH  (BB*HH)         // 2048

// branch N sizes (cols of the proj GEMM): N_i = NBH * P_i
#define N0   (NBH*2)         // 4096
#define N1   (NBH*4)         // 8192
#define N2   (NBH*8)         // 16384
#define NTOT (N0+N1+N2)      // 28672

typedef __attribute__((ext_vector_type(8))) short bf16x8;
typedef __attribute__((ext_vector_type(4))) float f32x4;

// ---------------------------------------------------------------------------
// k_mats1: A[i][c][d] = M_i[c][d] = sum_o Wf[i,o,c]*Wp[i,o,d]   (bf16, rows 0..255)
//          E[i][o][c2] = sum_c3 Wfuse[o, i*C+c3]*Wo[i,c3,c2]    (fp32 temp)
// ---------------------------------------------------------------------------
__global__ __launch_bounds__(256) void k_mats1(
    const float* __restrict__ Wp, const float* __restrict__ Wf,
    const float* __restrict__ Wo, const float* __restrict__ Wfu,
    __hip_bfloat16* __restrict__ A, float* __restrict__ E)
{
    int idx = blockIdx.x;
    int t = threadIdx.x;
    if (idx < 3*CC) {                       // M_i rows
        int i = idx >> 8, c = idx & 255;
        const float* wf = Wf + (size_t)i*MAT;
        const float* wp = Wp + (size_t)i*MAT;
        float acc = 0.f;
        for (int o = 0; o < CC; ++o)
            acc += wf[o*CC + c] * wp[o*CC + t];      // wf uniform, wp coalesced
        A[(size_t)i*512*CC + (size_t)c*CC + t] = __float2bfloat16(acc);
    } else {                                // E_i
        idx -= 3*CC;
        int i = idx >> 8, o = idx & 255;
        const float* wo = Wo + (size_t)i*MAT;
        const float* wfu = Wfu + (size_t)o*(3*CC) + i*CC;
        float acc = 0.f;
        for (int c3 = 0; c3 < CC; ++c3)
            acc += wfu[c3] * wo[c3*CC + t];          // wfu uniform, wo coalesced
        E[(size_t)i*MAT + (size_t)o*CC + t] = acc;
    }
}

// ---------------------------------------------------------------------------
// k_mats2: A[i][256+o][d] = V_i[o][d] = sum_c E_i[o][c]*Wp[i,c,d]   (bf16)
// ---------------------------------------------------------------------------
__global__ __launch_bounds__(256) void k_mats2(
    const float* __restrict__ Wp, const float* __restrict__ E,
    __hip_bfloat16* __restrict__ A)
{
    int idx = blockIdx.x;
    int i = idx >> 8, o = idx & 255;
    int t = threadIdx.x;
    const float* e = E + (size_t)i*MAT + (size_t)o*CC;
    const float* wp = Wp + (size_t)i*MAT;
    float acc = 0.f;
    for (int c = 0; c < CC; ++c)
        acc += e[c] * wp[c*CC + t];                  // e uniform, wp coalesced
    A[(size_t)i*512*CC + (size_t)(256+o)*CC + t] = __float2bfloat16(acc);
}

// ---------------------------------------------------------------------------
// k_pool: pooled means -> Bt (bf16, transposed: Bt_i[n][d], n = bh*P_i + p)
// block = 256 threads over one (b,h) row; 16-lane shuffle reduce -> 8 fine bins
// ---------------------------------------------------------------------------
__global__ __launch_bounds__(256) void k_pool(
    const float* __restrict__ x, __hip_bfloat16* __restrict__ Bt)
{
    int bh = blockIdx.x;
    int b = bh >> 7, h = bh & 127;
    int t = threadIdx.x;
    int w = t & 127, chalf = t >> 7;
    __shared__ float bins[CC][9];
    size_t base = (size_t)b*CC*HW + (size_t)h*WW + w;
    for (int i = 0; i < 128; ++i) {
        int c = chalf*128 + i;
        float v = x[base + (size_t)c*HW];
        v += __shfl_xor(v, 1);
        v += __shfl_xor(v, 2);
        v += __shfl_xor(v, 4);
        v += __shfl_xor(v, 8);
        if ((w & 15) == 0) bins[c][w >> 4] = v;
    }
    __syncthreads();
    int c = t;
    float b8[8];
    #pragma unroll
    for (int j = 0; j < 8; ++j) b8[j] = bins[c][j];

    __hip_bfloat16* B0 = Bt;                              // [N0][CC]
    __hip_bfloat16* B1 = Bt + (size_t)N0*CC;              // [N1][CC]
    __hip_bfloat16* B2 = Bt + (size_t)(N0+N1)*CC;         // [N2][CC]
    B0[((size_t)bh*2 + 0)*CC + c] = __float2bfloat16((b8[0]+b8[1]+b8[2]+b8[3]) * (1.f/64.f));
    B0[((size_t)bh*2 + 1)*CC + c] = __float2bfloat16((b8[4]+b8[5]+b8[6]+b8[7]) * (1.f/64.f));
    #pragma unroll
    for (int j = 0; j < 4; ++j)
        B1[((size_t)bh*4 + j)*CC + c] = __float2bfloat16((b8[2*j]+b8[2*j+1]) * (1.f/32.f));
    #pragma unroll
    for (int j = 0; j < 8; ++j)
        B2[((size_t)bh*8 + j)*CC + c] = __float2bfloat16(b8[j] * (1.f/16.f));
}

// ---------------------------------------------------------------------------
// k_gemm: per branch i: C_i[r][n] = sum_d A_i[r][d] * Bt_i[n][d]
// A_i : [512][256] bf16 (rows 0..255 = M_i, 256..511 = V_i)
// block = 256 thr (4 waves), block tile 128x128, wave tile 64x64, direct loads
// ---------------------------------------------------------------------------
__global__ __launch_bounds__(256) void k_gemm(
    const __hip_bfloat16* __restrict__ A,
    const __hip_bfloat16* __restrict__ Bt,
    float* __restrict__ C)
{
    int blk = blockIdx.x;
    int br, lb, N;
    size_t aoff, btoff, coff;
    if (blk < 4*(N0/128)) {
        br = 0; lb = blk; N = N0; aoff = 0; btoff = 0; coff = 0;
    } else if (blk < 4*(N0/128) + 4*(N1/128)) {
        br = 1; lb = blk - 4*(N0/128); N = N1;
        aoff = (size_t)512*CC; btoff = (size_t)N0*CC; coff = (size_t)512*N0;
    } else {
        br = 2; lb = blk - 4*(N0/128) - 4*(N1/128); N = N2;
        aoff = (size_t)2*512*CC; btoff = (size_t)(N0+N1)*CC; coff = (size_t)512*(N0+N1);
    }
    (void)br;
    const __hip_bfloat16* Ab  = A  + aoff;
    const __hip_bfloat16* Bb  = Bt + btoff;
    float* Cb = C + coff;

    int rb = lb & 3, cb = lb >> 2;          // 4 row-blocks fastest (share B tile)
    int w = threadIdx.x >> 6, lane = threadIdx.x & 63;
    int wr = w >> 1, wc = w & 1;
    int row0 = rb*128 + wr*64;
    int col0 = cb*128 + wc*64;
    int lr = lane & 15, lk = (lane >> 4) * 8;

    f32x4 acc[4][4] = {};
    for (int kk = 0; kk < CC; kk += 32) {
        bf16x8 af[4], bfr[4];
        #pragma unroll
        for (int m = 0; m < 4; ++m)
            af[m] = *reinterpret_cast<const bf16x8*>(Ab + (size_t)(row0 + m*16 + lr)*CC + kk + lk);
        #pragma unroll
        for (int n = 0; n < 4; ++n)
            bfr[n] = *reinterpret_cast<const bf16x8*>(Bb + (size_t)(col0 + n*16 + lr)*CC + kk + lk);
        #pragma unroll
        for (int m = 0; m < 4; ++m)
            #pragma unroll
            for (int n = 0; n < 4; ++n)
                acc[m][n] = __builtin_amdgcn_mfma_f32_16x16x32_bf16(af[m], bfr[n], acc[m][n], 0, 0, 0);
    }

    int cr = (lane >> 4) * 4, ccol = lane & 15;
    #pragma unroll
    for (int m = 0; m < 4; ++m)
        #pragma unroll
        for (int n = 0; n < 4; ++n)
            #pragma unroll
            for (int j = 0; j < 4; ++j)
                Cb[(size_t)(row0 + m*16 + cr + j)*N + col0 + n*16 + ccol] = acc[m][n][j];
}

// ---------------------------------------------------------------------------
// k_main: per (b,h) row: att logits via mproj (C rows 0..255), softmax,
// out = x + att @ vproj (C rows 256..511). All proj reads wave-uniform.
// ---------------------------------------------------------------------------
template<int L>
__device__ __forceinline__ void softmax_l(float* a) {
    float m = a[0];
    #pragma unroll
    for (int j = 1; j < L; ++j) m = fmaxf(m, a[j]);
    float s = 0.f;
    #pragma unroll
    for (int j = 0; j < L; ++j) { a[j] = __expf(a[j] - m); s += a[j]; }
    float r = 1.f / s;
    #pragma unroll
    for (int j = 0; j < L; ++j) a[j] *= r;
}

__global__ __launch_bounds__(128) void k_main(
    const float* __restrict__ x, const float* __restrict__ C,
    float* __restrict__ out)
{
    int bh = blockIdx.x;
    int b = bh >> 7, h = bh & 127;
    int w = threadIdx.x;
    const float* C0 = C;                                  // [512][N0]
    const float* C1 = C + (size_t)512*N0;                 // [512][N1]
    const float* C2 = C + (size_t)512*(N0+N1);            // [512][N2]
    size_t base = (size_t)b*CC*HW + (size_t)h*WW + w;
    int n0 = bh*2, n1 = bh*4, n2 = bh*8;

    float att[14];
    #pragma unroll
    for (int p = 0; p < 14; ++p) att[p] = 0.f;

    for (int c = 0; c < CC; ++c) {
        float xv = x[base + (size_t)c*HW];
        const float* p0 = C0 + (size_t)c*N0 + n0;         // uniform
        const float* p1 = C1 + (size_t)c*N1 + n1;
        const float* p2 = C2 + (size_t)c*N2 + n2;
        att[0] += xv * p0[0];  att[1] += xv * p0[1];
        #pragma unroll
        for (int j = 0; j < 4; ++j) att[2+j] += xv * p1[j];
        #pragma unroll
        for (int j = 0; j < 8; ++j) att[6+j] += xv * p2[j];
    }
    #pragma unroll
    for (int p = 0; p < 14; ++p) att[p] *= 0.0625f;       // 1/sqrt(256)

    softmax_l<2>(att + 0);
    softmax_l<4>(att + 2);
    softmax_l<8>(att + 6);

    for (int o = 0; o < CC; ++o) {
        float acc = x[base + (size_t)o*HW];
        const float* q0 = C0 + (size_t)(256+o)*N0 + n0;   // uniform
        const float* q1 = C1 + (size_t)(256+o)*N1 + n1;
        const float* q2 = C2 + (size_t)(256+o)*N2 + n2;
        acc += att[0]*q0[0] + att[1]*q0[1];
        #pragma unroll
        for (int j = 0; j < 4; ++j) acc += att[2+j]*q1[j];
        #pragma unroll
        for (int j = 0; j < 8; ++j) acc += att[6+j]*q2[j];
        out[base + (size_t)o*HW] = acc;
    }
}

// ---------------------------------------------------------------------------
extern "C" void kernel_launch(void* const* d_in, const int* in_sizes, int n_in,
                              void* d_out, int out_size, void* d_ws, size_t ws_size,
                              hipStream_t stream)
{
    (void)in_sizes; (void)n_in; (void)out_size; (void)ws_size;
    const float* x   = (const float*)d_in[0];
    const float* Wp  = (const float*)d_in[1];
    const float* Wf  = (const float*)d_in[2];
    const float* Wo  = (const float*)d_in[3];
    const float* Wfu = (const float*)d_in[4];
    float* out = (float*)d_out;

    // workspace layout (bytes):
    //   E    fp32 3*MAT            =   786432
    //   A    bf16 3*512*256        =   786432
    //   Bt   bf16 NTOT*256         = 14680064
    //   C    fp32 512*NTOT         = 58720256      total ~75 MB
    char* wsb = (char*)d_ws;
    float*          E  = (float*)wsb;
    __hip_bfloat16* A  = (__hip_bfloat16*)(wsb + 786432);
    __hip_bfloat16* Bt = (__hip_bfloat16*)(wsb + 786432 + 786432);
    float*          C  = (float*)(wsb + 786432 + 786432 + 14680064);

    k_mats1<<<dim3(6*CC), dim3(256), 0, stream>>>(Wp, Wf, Wo, Wfu, A, E);
    k_mats2<<<dim3(3*CC), dim3(256), 0, stream>>>(Wp, E, A);
    k_pool <<<dim3(NBH),  dim3(256), 0, stream>>>(x, Bt);
    k_gemm <<<dim3(4*(N0/128) + 4*(N1/128) + 4*(N2/128)), dim3(256), 0, stream>>>(A, Bt, C);
    k_main <<<dim3(NBH),  dim3(128), 0, stream>>>(x, C, out);
}

// Round 3
// 395.446 us; speedup vs baseline: 1.4692x; 1.0898x over previous
//
#include <hip/hip_runtime.h>
#include <hip/hip_bf16.h>
#include <math.h>

#define CC   256
#define HW   (128*128)       // 16384
#define MAT  (CC*CC)         // 65536
#define NBH  2048
#define N0   4096
#define N1   8192
#define N2   16384

typedef __attribute__((ext_vector_type(8))) short bf16x8;
typedef __attribute__((ext_vector_type(4))) float f32x4;

// ---------------------------------------------------------------------------
// k_mats1: A[i][c][d] = M_i[c][d] = sum_o Wf[i,o,c]*Wp[i,o,d]   (bf16 rows 0..255)
//          E[i][o][c2] = sum_c3 Wfuse[o, i*C+c3]*Wo[i,c3,c2]    (fp32 temp)
// ---------------------------------------------------------------------------
__global__ __launch_bounds__(256) void k_mats1(
    const float* __restrict__ Wp, const float* __restrict__ Wf,
    const float* __restrict__ Wo, const float* __restrict__ Wfu,
    __hip_bfloat16* __restrict__ A, float* __restrict__ E)
{
    int idx = blockIdx.x;
    int t = threadIdx.x;
    if (idx < 3*CC) {
        int i = idx >> 8, c = idx & 255;
        const float* wf = Wf + (size_t)i*MAT;
        const float* wp = Wp + (size_t)i*MAT;
        float acc = 0.f;
        for (int o = 0; o < CC; ++o)
            acc += wf[o*CC + c] * wp[o*CC + t];      // wf uniform, wp coalesced
        A[(size_t)i*512*CC + (size_t)c*CC + t] = __float2bfloat16(acc);
    } else {
        idx -= 3*CC;
        int i = idx >> 8, o = idx & 255;
        const float* wo = Wo + (size_t)i*MAT;
        const float* wfu = Wfu + (size_t)o*(3*CC) + i*CC;
        float acc = 0.f;
        for (int c3 = 0; c3 < CC; ++c3)
            acc += wfu[c3] * wo[c3*CC + t];          // wfu uniform, wo coalesced
        E[(size_t)i*MAT + (size_t)o*CC + t] = acc;
    }
}

// ---------------------------------------------------------------------------
// k_mats2: A[i][256+o][d] = V_i[o][d] = sum_c E_i[o][c]*Wp[i,c,d]   (bf16)
// ---------------------------------------------------------------------------
__global__ __launch_bounds__(256) void k_mats2(
    const float* __restrict__ Wp, const float* __restrict__ E,
    __hip_bfloat16* __restrict__ A)
{
    int idx = blockIdx.x;
    int i = idx >> 8, o = idx & 255;
    int t = threadIdx.x;
    const float* e = E + (size_t)i*MAT + (size_t)o*CC;
    const float* wp = Wp + (size_t)i*MAT;
    float acc = 0.f;
    for (int c = 0; c < CC; ++c)
        acc += e[c] * wp[c*CC + t];
    A[(size_t)i*512*CC + (size_t)(256+o)*CC + t] = __float2bfloat16(acc);
}

// ---------------------------------------------------------------------------
// k_pool v3: 2 bh per block, float4 loads. bins -> Bt (bf16, [n][256] per branch)
// thread: hh = which bh, cg = c-group (4), q = w-quad (32)
// ---------------------------------------------------------------------------
__global__ __launch_bounds__(256) void k_pool(
    const float* __restrict__ x, __hip_bfloat16* __restrict__ Bt)
{
    int t = threadIdx.x;
    int hh = t >> 7;
    int cg = (t >> 5) & 3;
    int q  = t & 31;
    int bh = blockIdx.x*2 + hh;
    int b = bh >> 7, h = bh & 127;
    __shared__ float bins[2][256][9];
    size_t rowbase = ((size_t)b*CC)*HW + (size_t)h*128;
    #pragma unroll 4
    for (int cc = 0; cc < 64; ++cc) {
        int c = cc*4 + cg;
        float4 v = *reinterpret_cast<const float4*>(&x[rowbase + (size_t)c*HW + q*4]);
        float s = v.x + v.y + v.z + v.w;
        s += __shfl_xor(s, 1);
        s += __shfl_xor(s, 2);                       // sum over 16 w (4 quads)
        if ((q & 3) == 0) bins[hh][c][q >> 2] = s;
    }
    __syncthreads();
    __hip_bfloat16* B0 = Bt;                              // [N0][CC]
    __hip_bfloat16* B1 = Bt + (size_t)N0*CC;              // [N1][CC]
    __hip_bfloat16* B2 = Bt + (size_t)(N0+N1)*CC;         // [N2][CC]
    #pragma unroll 2
    for (int rep = 0; rep < 2; ++rep) {
        int c = rep*128 + (t & 127);
        int hh2 = t >> 7;
        int bh2 = blockIdx.x*2 + hh2;
        float b8[8];
        #pragma unroll
        for (int j = 0; j < 8; ++j) b8[j] = bins[hh2][c][j];
        B0[((size_t)bh2*2 + 0)*CC + c] = __float2bfloat16((b8[0]+b8[1]+b8[2]+b8[3]) * (1.f/64.f));
        B0[((size_t)bh2*2 + 1)*CC + c] = __float2bfloat16((b8[4]+b8[5]+b8[6]+b8[7]) * (1.f/64.f));
        #pragma unroll
        for (int j = 0; j < 4; ++j)
            B1[((size_t)bh2*4 + j)*CC + c] = __float2bfloat16((b8[2*j]+b8[2*j+1]) * (1.f/32.f));
        #pragma unroll
        for (int j = 0; j < 8; ++j)
            B2[((size_t)bh2*8 + j)*CC + c] = __float2bfloat16(b8[j] * (1.f/16.f));
    }
}

// ---------------------------------------------------------------------------
// k_gemm v3: 1792 blocks x 128 thr (2 waves). Block tile 128 rows x 64 cols,
// wave tile 64x64. Epilogue scatters into per-bh layout Cc[bh][512][16] fp32.
// rows 0..255 = mp (c), 256..511 = vp (o); cols: p at branch offset {0,2,6}.
// ---------------------------------------------------------------------------
__global__ __launch_bounds__(128) void k_gemm(
    const __hip_bfloat16* __restrict__ A,
    const __hip_bfloat16* __restrict__ Bt,
    float* __restrict__ Cc)
{
    int blk = blockIdx.x;
    int br, lb, LP, poff;
    if (blk < 256)      { br = 0; lb = blk;       LP = 1; poff = 0; }
    else if (blk < 768) { br = 1; lb = blk - 256; LP = 2; poff = 2; }
    else                { br = 2; lb = blk - 768; LP = 3; poff = 6; }
    size_t aoff  = (size_t)br*512*CC;
    size_t btoff = (br == 0) ? 0 : (br == 1 ? (size_t)N0*CC : (size_t)(N0+N1)*CC);
    const __hip_bfloat16* Ab = A  + aoff;
    const __hip_bfloat16* Bb = Bt + btoff;

    int rb = lb & 3, cb = lb >> 2;
    int wv = threadIdx.x >> 6, lane = threadIdx.x & 63;
    int row0 = rb*128 + wv*64;
    int col0 = cb*64;
    int lr = lane & 15, lk = (lane >> 4) * 8;

    f32x4 acc[4][4] = {};
    for (int kk = 0; kk < CC; kk += 32) {
        bf16x8 af[4], bfr[4];
        #pragma unroll
        for (int m = 0; m < 4; ++m)
            af[m] = *reinterpret_cast<const bf16x8*>(Ab + (size_t)(row0 + m*16 + lr)*CC + kk + lk);
        #pragma unroll
        for (int n = 0; n < 4; ++n)
            bfr[n] = *reinterpret_cast<const bf16x8*>(Bb + (size_t)(col0 + n*16 + lr)*CC + kk + lk);
        #pragma unroll
        for (int m = 0; m < 4; ++m)
            #pragma unroll
            for (int n = 0; n < 4; ++n)
                acc[m][n] = __builtin_amdgcn_mfma_f32_16x16x32_bf16(af[m], bfr[n], acc[m][n], 0, 0, 0);
    }

    int cr = (lane >> 4) * 4, ccol = lane & 15;
    int pm = (1 << LP) - 1;
    #pragma unroll
    for (int m = 0; m < 4; ++m) {
        #pragma unroll
        for (int n = 0; n < 4; ++n) {
            int colg = col0 + n*16 + ccol;
            int bh = colg >> LP, p = colg & pm;
            float* dst = Cc + (size_t)bh*8192 + poff + p;
            #pragma unroll
            for (int j = 0; j < 4; ++j) {
                int r = row0 + m*16 + cr + j;
                dst[r*16] = acc[m][n][j];
            }
        }
    }
}

// ---------------------------------------------------------------------------
// k_main v3: one block per bh, 256 thr. Wave-pair g=0: even c/o, g=1: odd.
// Pass A: att logits (mp rows of Cc, scalar loads), LDS reduce + softmax.
// Pass B: out = x + att.vp, att in regs, vp scalar loads.
// ---------------------------------------------------------------------------
template<int L>
__device__ __forceinline__ void softmax_l(float* a) {
    float m = a[0];
    #pragma unroll
    for (int j = 1; j < L; ++j) m = fmaxf(m, a[j]);
    float s = 0.f;
    #pragma unroll
    for (int j = 0; j < L; ++j) { a[j] = __expf(a[j] - m); s += a[j]; }
    float r = 1.f / s;
    #pragma unroll
    for (int j = 0; j < L; ++j) a[j] *= r;
}

__global__ __launch_bounds__(256) void k_main(
    const float* __restrict__ x, const float* __restrict__ Cc,
    float* __restrict__ out)
{
    int bh = blockIdx.x;
    int b = bh >> 7, h = bh & 127;
    int t = threadIdx.x;
    int w = t & 127;
    int g = __builtin_amdgcn_readfirstlane(t >> 7);   // wave-pair id, in SGPR
    const float* Cb = Cc + (size_t)bh * 8192;
    size_t base = ((size_t)b*CC)*HW + (size_t)h*128 + w;
    __shared__ float att_s[128][17];

    float att[14];
    #pragma unroll
    for (int p = 0; p < 14; ++p) att[p] = 0.f;

    #pragma unroll 4
    for (int cc = 0; cc < 128; ++cc) {
        int c = cc*2 + g;
        float xv = x[base + (size_t)c*HW];
        const float* mp = Cb + c*16;                  // scalar (SGPR) address
        #pragma unroll
        for (int p = 0; p < 14; ++p) att[p] += xv * mp[p];
    }

    if (g == 1) {
        #pragma unroll
        for (int p = 0; p < 14; ++p) att_s[w][p] = att[p];
    }
    __syncthreads();
    if (g == 0) {
        #pragma unroll
        for (int p = 0; p < 14; ++p) att[p] = (att[p] + att_s[w][p]) * 0.0625f;
        softmax_l<2>(att + 0);
        softmax_l<4>(att + 2);
        softmax_l<8>(att + 6);
        #pragma unroll
        for (int p = 0; p < 14; ++p) att_s[w][p] = att[p];
    }
    __syncthreads();
    #pragma unroll
    for (int p = 0; p < 14; ++p) att[p] = att_s[w][p];

    #pragma unroll 2
    for (int oo = 0; oo < 128; ++oo) {
        int o = oo*2 + g;
        float acc = x[base + (size_t)o*HW];
        const float* vp = Cb + (256 + o)*16;          // scalar (SGPR) address
        #pragma unroll
        for (int p = 0; p < 14; ++p) acc += att[p] * vp[p];
        out[base + (size_t)o*HW] = acc;
    }
}

// ---------------------------------------------------------------------------
extern "C" void kernel_launch(void* const* d_in, const int* in_sizes, int n_in,
                              void* d_out, int out_size, void* d_ws, size_t ws_size,
                              hipStream_t stream)
{
    (void)in_sizes; (void)n_in; (void)out_size; (void)ws_size;
    const float* x   = (const float*)d_in[0];
    const float* Wp  = (const float*)d_in[1];
    const float* Wf  = (const float*)d_in[2];
    const float* Wo  = (const float*)d_in[3];
    const float* Wfu = (const float*)d_in[4];
    float* out = (float*)d_out;

    // workspace layout (bytes):
    //   E    fp32 3*MAT              @ 0         =   786432
    //   A    bf16 3*512*256          @ 786432    =   786432
    //   Bt   bf16 28672*256          @ 1572864   = 14680064
    //   Cc   fp32 2048*512*16        @ 16252928  = 67108864   total ~83.4 MB
    char* wsb = (char*)d_ws;
    float*          E  = (float*)wsb;
    __hip_bfloat16* A  = (__hip_bfloat16*)(wsb + 786432);
    __hip_bfloat16* Bt = (__hip_bfloat16*)(wsb + 1572864);
    float*          Cc = (float*)(wsb + 16252928);

    k_mats1<<<dim3(6*CC),  dim3(256), 0, stream>>>(Wp, Wf, Wo, Wfu, A, E);
    k_mats2<<<dim3(3*CC),  dim3(256), 0, stream>>>(Wp, E, A);
    k_pool <<<dim3(NBH/2), dim3(256), 0, stream>>>(x, Bt);
    k_gemm <<<dim3(1792),  dim3(128), 0, stream>>>(A, Bt, Cc);
    k_main <<<dim3(NBH),   dim3(256), 0, stream>>>(x, Cc, out);
}

// Round 4
// 342.252 us; speedup vs baseline: 1.6976x; 1.1554x over previous
//
#include <hip/hip_runtime.h>
#include <hip/hip_bf16.h>
#include <math.h>

#define CC   256
#define HW   (128*128)       // 16384
#define MAT  (CC*CC)         // 65536
#define NBH  2048
#define N0   4096
#define N1   8192
#define N2   16384

typedef __attribute__((ext_vector_type(8))) short bf16x8;
typedef __attribute__((ext_vector_type(4))) float f32x4;

// ---------------------------------------------------------------------------
// k_mats1: A[i][c][d] = M_i[c][d] = sum_o Wf[i,o,c]*Wp[i,o,d]   (bf16 rows 0..255)
//          E[i][o][c2] = sum_c3 Wfuse[o, i*C+c3]*Wo[i,c3,c2]    (fp32 temp)
// ---------------------------------------------------------------------------
__global__ __launch_bounds__(256) void k_mats1(
    const float* __restrict__ Wp, const float* __restrict__ Wf,
    const float* __restrict__ Wo, const float* __restrict__ Wfu,
    __hip_bfloat16* __restrict__ A, float* __restrict__ E)
{
    int idx = blockIdx.x;
    int t = threadIdx.x;
    if (idx < 3*CC) {
        int i = idx >> 8, c = idx & 255;
        const float* wf = Wf + (size_t)i*MAT;
        const float* wp = Wp + (size_t)i*MAT;
        float acc = 0.f;
        for (int o = 0; o < CC; ++o)
            acc += wf[o*CC + c] * wp[o*CC + t];
        A[(size_t)i*512*CC + (size_t)c*CC + t] = __float2bfloat16(acc);
    } else {
        idx -= 3*CC;
        int i = idx >> 8, o = idx & 255;
        const float* wo = Wo + (size_t)i*MAT;
        const float* wfu = Wfu + (size_t)o*(3*CC) + i*CC;
        float acc = 0.f;
        for (int c3 = 0; c3 < CC; ++c3)
            acc += wfu[c3] * wo[c3*CC + t];
        E[(size_t)i*MAT + (size_t)o*CC + t] = acc;
    }
}

// ---------------------------------------------------------------------------
// k_mats2: A[i][256+o][d] = V_i[o][d] = sum_c E_i[o][c]*Wp[i,c,d]   (bf16)
// ---------------------------------------------------------------------------
__global__ __launch_bounds__(256) void k_mats2(
    const float* __restrict__ Wp, const float* __restrict__ E,
    __hip_bfloat16* __restrict__ A)
{
    int idx = blockIdx.x;
    int i = idx >> 8, o = idx & 255;
    int t = threadIdx.x;
    const float* e = E + (size_t)i*MAT + (size_t)o*CC;
    const float* wp = Wp + (size_t)i*MAT;
    float acc = 0.f;
    for (int c = 0; c < CC; ++c)
        acc += e[c] * wp[c*CC + t];
    A[(size_t)i*512*CC + (size_t)(256+o)*CC + t] = __float2bfloat16(acc);
}

// ---------------------------------------------------------------------------
// k_poolA: one (b,c) per block. Reads x[b][c][:][:] = 64 KB fully contiguous.
// Produces binsG[b][c][h][8] (fp32, 4 KB contiguous per block).
// ---------------------------------------------------------------------------
__global__ __launch_bounds__(256) void k_poolA(
    const float* __restrict__ x, float* __restrict__ binsG)
{
    int bc = blockIdx.x;                 // b*256 + c
    int t = threadIdx.x;
    const float4* xp = (const float4*)(x + (size_t)bc*HW);
    __shared__ float bins[128][9];       // [h][bin], pad 9
    int hb = t >> 5;                     // h sub-index within i-group
    int bin = (t & 31) >> 2;
    #pragma unroll 4
    for (int i = 0; i < 16; ++i) {
        float4 v = xp[i*256 + t];
        float s = v.x + v.y + v.z + v.w;
        s += __shfl_xor(s, 1);
        s += __shfl_xor(s, 2);           // sum of 16 w
        if ((t & 3) == 0) bins[i*8 + hb][bin] = s;
    }
    __syncthreads();
    // write 1024 floats coalesced: thread t -> h = t>>1, b0 = (t&1)*4
    int h = t >> 1, b0 = (t & 1) * 4;
    float4 o;
    o.x = bins[h][b0+0]; o.y = bins[h][b0+1];
    o.z = bins[h][b0+2]; o.w = bins[h][b0+3];
    ((float4*)binsG)[(size_t)bc*256 + t] = o;
}

// ---------------------------------------------------------------------------
// k_poolB: one bh per block, 256 thr (thread = c). Reads binsG[b][c][h][8],
// emits Bt (bf16): B0/B1/B2 rows, coalesced writes along c.
// ---------------------------------------------------------------------------
__global__ __launch_bounds__(256) void k_poolB(
    const float* __restrict__ binsG, __hip_bfloat16* __restrict__ Bt)
{
    int bh = blockIdx.x;
    int b = bh >> 7, h = bh & 127;
    int c = threadIdx.x;
    const float* g = binsG + (((size_t)b*256 + c)*128 + h)*8;
    float4 lo = *(const float4*)(g);
    float4 hi = *(const float4*)(g + 4);
    float b8[8] = {lo.x, lo.y, lo.z, lo.w, hi.x, hi.y, hi.z, hi.w};

    __hip_bfloat16* B0 = Bt;
    __hip_bfloat16* B1 = Bt + (size_t)N0*CC;
    __hip_bfloat16* B2 = Bt + (size_t)(N0+N1)*CC;
    B0[((size_t)bh*2 + 0)*CC + c] = __float2bfloat16((b8[0]+b8[1]+b8[2]+b8[3]) * (1.f/64.f));
    B0[((size_t)bh*2 + 1)*CC + c] = __float2bfloat16((b8[4]+b8[5]+b8[6]+b8[7]) * (1.f/64.f));
    #pragma unroll
    for (int j = 0; j < 4; ++j)
        B1[((size_t)bh*4 + j)*CC + c] = __float2bfloat16((b8[2*j]+b8[2*j+1]) * (1.f/32.f));
    #pragma unroll
    for (int j = 0; j < 8; ++j)
        B2[((size_t)bh*8 + j)*CC + c] = __float2bfloat16(b8[j] * (1.f/16.f));
}

// ---------------------------------------------------------------------------
// k_gemm: 1792 blocks x 128 thr. Block tile 128x64, wave tile 64x64.
// Epilogue scatters into Cc[bh][512][16] fp32 (rows 0..255 mp, 256..511 vp).
// ---------------------------------------------------------------------------
__global__ __launch_bounds__(128) void k_gemm(
    const __hip_bfloat16* __restrict__ A,
    const __hip_bfloat16* __restrict__ Bt,
    float* __restrict__ Cc)
{
    int blk = blockIdx.x;
    int br, lb, LP, poff;
    if (blk < 256)      { br = 0; lb = blk;       LP = 1; poff = 0; }
    else if (blk < 768) { br = 1; lb = blk - 256; LP = 2; poff = 2; }
    else                { br = 2; lb = blk - 768; LP = 3; poff = 6; }
    size_t aoff  = (size_t)br*512*CC;
    size_t btoff = (br == 0) ? 0 : (br == 1 ? (size_t)N0*CC : (size_t)(N0+N1)*CC);
    const __hip_bfloat16* Ab = A  + aoff;
    const __hip_bfloat16* Bb = Bt + btoff;

    int rb = lb & 3, cb = lb >> 2;
    int wv = threadIdx.x >> 6, lane = threadIdx.x & 63;
    int row0 = rb*128 + wv*64;
    int col0 = cb*64;
    int lr = lane & 15, lk = (lane >> 4) * 8;

    f32x4 acc[4][4] = {};
    for (int kk = 0; kk < CC; kk += 32) {
        bf16x8 af[4], bfr[4];
        #pragma unroll
        for (int m = 0; m < 4; ++m)
            af[m] = *reinterpret_cast<const bf16x8*>(Ab + (size_t)(row0 + m*16 + lr)*CC + kk + lk);
        #pragma unroll
        for (int n = 0; n < 4; ++n)
            bfr[n] = *reinterpret_cast<const bf16x8*>(Bb + (size_t)(col0 + n*16 + lr)*CC + kk + lk);
        #pragma unroll
        for (int m = 0; m < 4; ++m)
            #pragma unroll
            for (int n = 0; n < 4; ++n)
                acc[m][n] = __builtin_amdgcn_mfma_f32_16x16x32_bf16(af[m], bfr[n], acc[m][n], 0, 0, 0);
    }

    int cr = (lane >> 4) * 4, ccol = lane & 15;
    int pm = (1 << LP) - 1;
    #pragma unroll
    for (int m = 0; m < 4; ++m) {
        #pragma unroll
        for (int n = 0; n < 4; ++n) {
            int colg = col0 + n*16 + ccol;
            int bh = colg >> LP, p = colg & pm;
            float* dst = Cc + (size_t)bh*8192 + poff + p;
            #pragma unroll
            for (int j = 0; j < 4; ++j) {
                int r = row0 + m*16 + cr + j;
                dst[r*16] = acc[m][n][j];
            }
        }
    }
}

// ---------------------------------------------------------------------------
// k_main v4: one bh per block, 256 thr = 4 waves. Thread owns w-pair (float2);
// wave wv handles c ≡ wv (mod 4) -> mp/vp stay wave-uniform s_loads.
// att2 reduced across waves via LDS; softmax in wave 0; pass B fused residual.
// ---------------------------------------------------------------------------
template<int L>
__device__ __forceinline__ void softmax2(float2* a) {
    float mx = a[0].x, my = a[0].y;
    #pragma unroll
    for (int j = 1; j < L; ++j) { mx = fmaxf(mx, a[j].x); my = fmaxf(my, a[j].y); }
    float sx = 0.f, sy = 0.f;
    #pragma unroll
    for (int j = 0; j < L; ++j) {
        a[j].x = __expf(a[j].x - mx); sx += a[j].x;
        a[j].y = __expf(a[j].y - my); sy += a[j].y;
    }
    float rx = 1.f / sx, ry = 1.f / sy;
    #pragma unroll
    for (int j = 0; j < L; ++j) { a[j].x *= rx; a[j].y *= ry; }
}

__global__ __launch_bounds__(256) void k_main(
    const float* __restrict__ x, const float* __restrict__ Cc,
    float* __restrict__ out)
{
    int bh = blockIdx.x;
    int b = bh >> 7, h = bh & 127;
    int t = threadIdx.x;
    int lane = t & 63;
    int wv = __builtin_amdgcn_readfirstlane(t >> 6);     // wave id 0..3
    const float* Cb = Cc + (size_t)bh * 8192;
    size_t base2 = (((size_t)b*CC)*HW + (size_t)h*128) >> 1;  // float2 index, +lane
    const float2* x2 = (const float2*)x;
    float2* out2 = (float2*)out;
    __shared__ float2 att_s[4][64][14];                  // 28672 B

    float2 att[14];
    #pragma unroll
    for (int p = 0; p < 14; ++p) att[p] = make_float2(0.f, 0.f);

    #pragma unroll 8
    for (int cc = 0; cc < 64; ++cc) {
        int c = cc*4 + wv;
        float2 xv = x2[base2 + (size_t)c*(HW/2) + lane];
        const float* mp = Cb + c*16;                     // s_load
        #pragma unroll
        for (int p = 0; p < 14; ++p) {
            att[p].x += xv.x * mp[p];
            att[p].y += xv.y * mp[p];
        }
    }

    #pragma unroll
    for (int p = 0; p < 14; ++p) att_s[wv][lane][p] = att[p];
    __syncthreads();
    if (wv == 0) {
        #pragma unroll
        for (int p = 0; p < 14; ++p) {
            float2 a1 = att_s[1][lane][p], a2 = att_s[2][lane][p], a3 = att_s[3][lane][p];
            att[p].x = (att[p].x + a1.x + a2.x + a3.x) * 0.0625f;
            att[p].y = (att[p].y + a1.y + a2.y + a3.y) * 0.0625f;
        }
        softmax2<2>(att + 0);
        softmax2<4>(att + 2);
        softmax2<8>(att + 6);
        #pragma unroll
        for (int p = 0; p < 14; ++p) att_s[0][lane][p] = att[p];
    }
    __syncthreads();
    #pragma unroll
    for (int p = 0; p < 14; ++p) att[p] = att_s[0][lane][p];

    #pragma unroll 8
    for (int oo = 0; oo < 64; ++oo) {
        int o = oo*4 + wv;
        float2 xv = x2[base2 + (size_t)o*(HW/2) + lane];
        const float* vp = Cb + (256 + o)*16;             // s_load
        float2 acc = xv;
        #pragma unroll
        for (int p = 0; p < 14; ++p) {
            acc.x += att[p].x * vp[p];
            acc.y += att[p].y * vp[p];
        }
        out2[base2 + (size_t)o*(HW/2) + lane] = acc;
    }
}

// ---------------------------------------------------------------------------
extern "C" void kernel_launch(void* const* d_in, const int* in_sizes, int n_in,
                              void* d_out, int out_size, void* d_ws, size_t ws_size,
                              hipStream_t stream)
{
    (void)in_sizes; (void)n_in; (void)out_size; (void)ws_size;
    const float* x   = (const float*)d_in[0];
    const float* Wp  = (const float*)d_in[1];
    const float* Wf  = (const float*)d_in[2];
    const float* Wo  = (const float*)d_in[3];
    const float* Wfu = (const float*)d_in[4];
    float* out = (float*)d_out;

    // workspace layout (bytes):
    //   E     fp32 3*MAT     @ 0         =   786432
    //   A     bf16 3*512*256 @ 786432    =   786432
    //   Bt    bf16 28672*256 @ 1572864   = 14680064
    //   Cc    fp32 2048*8192 @ 16252928  = 67108864   (binsG aliases Cc: 16.8 MB,
    //                                                  consumed by poolB before k_gemm writes Cc)
    char* wsb = (char*)d_ws;
    float*          E     = (float*)wsb;
    __hip_bfloat16* A     = (__hip_bfloat16*)(wsb + 786432);
    __hip_bfloat16* Bt    = (__hip_bfloat16*)(wsb + 1572864);
    float*          Cc    = (float*)(wsb + 16252928);
    float*          binsG = Cc;

    k_mats1<<<dim3(6*CC),  dim3(256), 0, stream>>>(Wp, Wf, Wo, Wfu, A, E);
    k_mats2<<<dim3(3*CC),  dim3(256), 0, stream>>>(Wp, E, A);
    k_poolA<<<dim3(4096),  dim3(256), 0, stream>>>(x, binsG);
    k_poolB<<<dim3(NBH),   dim3(256), 0, stream>>>(binsG, Bt);
    k_gemm <<<dim3(1792),  dim3(128), 0, stream>>>(A, Bt, Cc);
    k_main <<<dim3(NBH),   dim3(256), 0, stream>>>(x, Cc, out);
}